// Round 3
// baseline (129.362 us; speedup 1.0000x reference)
//
#include <hip/hip_runtime.h>
#include <hip/hip_cooperative_groups.h>

namespace cg = cooperative_groups;

#define NBOX 64
#define BLK  256

__device__ __forceinline__ unsigned long long range_mask(int x1, int x2, int base) {
    int lo = max(x1 - base, 0);
    int hi = min(x2 - base, 64);
    if (lo >= hi) return 0ull;
    unsigned long long m = (~0ull) >> (64 - (hi - lo));
    return m << lo;
}

__device__ __forceinline__ double wave_reduce(double v) {
    #pragma unroll
    for (int m = 1; m < 64; m <<= 1) v += __shfl_xor(v, m, 64);
    return v;
}

__global__ __launch_bounds__(BLK) void level_loss_fused(
    const float* __restrict__ att0, const float* __restrict__ att1,
    const float* __restrict__ att2, const float* __restrict__ att3,
    const float* __restrict__ att4,
    const float* __restrict__ bboxs,
    const int* __restrict__ Hp, const int* __restrict__ Wp,
    double* __restrict__ partial, float* __restrict__ out, int B)
{
    __shared__ unsigned long long smask[64][2];  // per-row x-coverage bitmask
    __shared__ int    s_hasvalid;
    __shared__ double swave[BLK / 64];

    const int tid  = threadIdx.x;
    const int bid  = blockIdx.x;
    const int nblk = gridDim.x;
    const int b    = bid >> 3;          // 8 block-slots per batch
    const int slot = bid & 7;
    const int lid   = (slot < 4) ? 0 : (slot - 3);   // level id 0..4
    const int chunk = (slot < 4) ? slot : 0;
    const int lw  = 7 - lid;            // log2(width)
    const int w   = 1 << lw;
    const int npx = w << lw;
    const int start = chunk * 4096;
    const int end   = min(npx, start + 4096);
    const int r0    = start >> lw;              // first row of this chunk
    const int nrows = (end - start) >> lw;

    const float Hf = (float)(*Hp);
    const float Wf = (float)(*Wp);

    // ---- wave 0: zero masks, then rasterize boxes into row bitmasks ----
    if (tid < 64) {
        smask[tid][0] = 0ull;
        smask[tid][1] = 0ull;

        const float* bb = bboxs + ((size_t)b * NBOX + tid) * 5;
        const float x1 = bb[0], y1 = bb[1], x2 = bb[2], y2 = bb[3], lab = bb[4];
        const bool valid = (lab != -1.0f) && (x1 <= Wf) && (y1 <= Hf)
                        && (x2 <= Wf) && (y2 <= Hf);
        const float area = (x2 - x1) * (y2 - y1);
        const float base = (float)(32 << lid);
        const float min_a = base * base * 0.5f;                 // exact in f32
        const double bd   = (double)base * 1.58;
        const float max_a = (float)(bd * bd * 2.0);             // f64 -> f32, matches JAX promotion
        const bool lv = valid && (area >= min_a) && (area <= max_a);

        const unsigned long long mvalid = __ballot(valid);
        if (tid == 0) s_hasvalid = (mvalid != 0ull) ? 1 : 0;

        if (lv) {
            const float sx = (float)w / Wf;   // powers of two: exact
            const float sy = (float)w / Hf;
            const int ix1 = (int)fmaxf(floorf(x1 * sx), 0.0f);
            const int iy1 = (int)fmaxf(floorf(y1 * sy), 0.0f);
            const int ix2 = (int)fminf(ceilf(x2 * sx) + 1.0f, (float)w);
            const int iy2 = (int)fminf(ceilf(y2 * sy) + 1.0f, (float)w);
            const int ys = max(iy1, r0);
            const int ye = min(iy2, r0 + nrows);
            const unsigned long long m0 = range_mask(ix1, ix2, 0);
            const unsigned long long m1 = range_mask(ix1, ix2, 64);
            for (int y = ys; y < ye; ++y) {
                if (m0) atomicOr(&smask[y - r0][0], m0);
                if (m1) atomicOr(&smask[y - r0][1], m1);
            }
        }
    }
    __syncthreads();

    const float* att = (lid == 0) ? att0 : (lid == 1) ? att1
                     : (lid == 2) ? att2 : (lid == 3) ? att3 : att4;
    const float* attb = att + (size_t)b * npx;

    const float lo_c = 1e-7f;
    const float hi_c = (float)(1.0 - 1e-7);   // matches jnp.clip upper bound

    double acc = 0.0;
    // one float4 per iter (4 consecutive px: same row, same 64-bit mask word)
    for (int p0 = start + tid * 4; p0 < end; p0 += BLK * 4) {
        const float4 a = *reinterpret_cast<const float4*>(attb + p0);
        const int y  = p0 >> lw;
        const int x0 = p0 & (w - 1);
        const unsigned int bits =
            (unsigned int)(smask[y - r0][(x0 >> 6) & 1] >> (x0 & 63)) & 0xFu;
        const float v0 = fminf(fmaxf(a.x, lo_c), hi_c);
        const float v1 = fminf(fmaxf(a.y, lo_c), hi_c);
        const float v2 = fminf(fmaxf(a.z, lo_c), hi_c);
        const float v3 = fminf(fmaxf(a.w, lo_c), hi_c);
        acc += (bits & 1u) ? (double)(-logf(v0)) : (double)(-log1pf(-v0));
        acc += (bits & 2u) ? (double)(-logf(v1)) : (double)(-log1pf(-v1));
        acc += (bits & 4u) ? (double)(-logf(v2)) : (double)(-log1pf(-v2));
        acc += (bits & 8u) ? (double)(-logf(v3)) : (double)(-log1pf(-v3));
    }

    // ---- block reduction: wave butterfly + tiny LDS combine ----
    acc = wave_reduce(acc);
    if ((tid & 63) == 0) swave[tid >> 6] = acc;
    __syncthreads();
    if (tid == 0) {
        double s = swave[0] + swave[1] + swave[2] + swave[3];
        const double wgt = s_hasvalid
            ? 1.0 / (5.0 * (double)B * (double)npx)
            : 0.0;
        __hip_atomic_store(&partial[bid], s * wgt,
                           __ATOMIC_RELEASE, __HIP_MEMORY_SCOPE_AGENT);
    }

    // ---- grid-wide sync, block 0 reduces all partials ----
    cg::this_grid().sync();

    if (bid == 0) {
        double v = 0.0;
        if (tid < nblk)
            v = __hip_atomic_load(&partial[tid],
                                  __ATOMIC_ACQUIRE, __HIP_MEMORY_SCOPE_AGENT);
        v = wave_reduce(v);
        if ((tid & 63) == 0) swave[tid >> 6] = v;
        __syncthreads();
        if (tid == 0)
            out[0] = (float)(swave[0] + swave[1] + swave[2] + swave[3]);
    }
}

extern "C" void kernel_launch(void* const* d_in, const int* in_sizes, int n_in,
                              void* d_out, int out_size, void* d_ws, size_t ws_size,
                              hipStream_t stream) {
    const float* att0  = (const float*)d_in[0];
    const float* att1  = (const float*)d_in[1];
    const float* att2  = (const float*)d_in[2];
    const float* att3  = (const float*)d_in[3];
    const float* att4  = (const float*)d_in[4];
    const float* bboxs = (const float*)d_in[5];
    const int*   Hp    = (const int*)d_in[6];
    const int*   Wp    = (const int*)d_in[7];
    float*  out     = (float*)d_out;
    double* partial = (double*)d_ws;          // nblk doubles
    int B = in_sizes[5] / (NBOX * 5);         // 32
    int nblk = B * 8;                          // 256 blocks

    void* args[] = { (void*)&att0, (void*)&att1, (void*)&att2, (void*)&att3,
                     (void*)&att4, (void*)&bboxs, (void*)&Hp, (void*)&Wp,
                     (void*)&partial, (void*)&out, (void*)&B };
    hipLaunchCooperativeKernel((void*)level_loss_fused,
                               dim3(nblk), dim3(BLK), args, 0, stream);
}

// Round 5
// 82.492 us; speedup vs baseline: 1.5682x; 1.5682x over previous
//
#include <hip/hip_runtime.h>

#define NBOX 64
#define BLK  256

__device__ __forceinline__ unsigned long long range_mask(int x1, int x2, int base) {
    int lo = max(x1 - base, 0);
    int hi = min(x2 - base, 64);
    if (lo >= hi) return 0ull;
    unsigned long long m = (~0ull) >> (64 - (hi - lo));
    return m << lo;
}

__device__ __forceinline__ double wave_reduce(double v) {
    #pragma unroll
    for (int m = 1; m < 64; m <<= 1) v += __shfl_xor(v, m, 64);
    return v;
}

__global__ __launch_bounds__(BLK) void level_loss_onekernel(
    const float* __restrict__ att0, const float* __restrict__ att1,
    const float* __restrict__ att2, const float* __restrict__ att3,
    const float* __restrict__ att4,
    const float* __restrict__ bboxs,
    const int* __restrict__ Hp, const int* __restrict__ Wp,
    double* __restrict__ partial, unsigned int* __restrict__ counter,
    float* __restrict__ out, int B, int nblk)
{
    __shared__ unsigned long long smask[64][2];  // per-row x-coverage bitmask
    __shared__ int    s_hasvalid;
    __shared__ int    s_last;
    __shared__ double swave[BLK / 64];

    const int tid  = threadIdx.x;
    const int bid  = blockIdx.x;
    const int b    = bid >> 3;          // 8 block-slots per batch
    const int slot = bid & 7;
    const int lid   = (slot < 4) ? 0 : (slot - 3);   // level id 0..4
    const int chunk = (slot < 4) ? slot : 0;
    const int lw  = 7 - lid;            // log2(width)
    const int w   = 1 << lw;
    const int npx = w << lw;
    const int start = chunk * 4096;
    const int end   = min(npx, start + 4096);
    const int r0    = start >> lw;              // first row of this chunk
    const int nrows = (end - start) >> lw;

    const float Hf = (float)(*Hp);
    const float Wf = (float)(*Wp);

    // ---- wave 0: zero masks, then rasterize boxes into row bitmasks ----
    if (tid < 64) {
        smask[tid][0] = 0ull;
        smask[tid][1] = 0ull;

        const float* bb = bboxs + ((size_t)b * NBOX + tid) * 5;
        const float x1 = bb[0], y1 = bb[1], x2 = bb[2], y2 = bb[3], lab = bb[4];
        const bool valid = (lab != -1.0f) && (x1 <= Wf) && (y1 <= Hf)
                        && (x2 <= Wf) && (y2 <= Hf);
        const float area = (x2 - x1) * (y2 - y1);
        const float base = (float)(32 << lid);
        const float min_a = base * base * 0.5f;                 // exact in f32
        const double bd   = (double)base * 1.58;
        const float max_a = (float)(bd * bd * 2.0);             // f64 -> f32, matches JAX promotion
        const bool lv = valid && (area >= min_a) && (area <= max_a);

        const unsigned long long mvalid = __ballot(valid);
        if (tid == 0) s_hasvalid = (mvalid != 0ull) ? 1 : 0;

        if (lv) {
            const float sx = (float)w / Wf;   // powers of two: exact
            const float sy = (float)w / Hf;
            const int ix1 = (int)fmaxf(floorf(x1 * sx), 0.0f);
            const int iy1 = (int)fmaxf(floorf(y1 * sy), 0.0f);
            const int ix2 = (int)fminf(ceilf(x2 * sx) + 1.0f, (float)w);
            const int iy2 = (int)fminf(ceilf(y2 * sy) + 1.0f, (float)w);
            const int ys = max(iy1, r0);
            const int ye = min(iy2, r0 + nrows);
            const unsigned long long m0 = range_mask(ix1, ix2, 0);
            const unsigned long long m1 = range_mask(ix1, ix2, 64);
            for (int y = ys; y < ye; ++y) {
                if (m0) atomicOr(&smask[y - r0][0], m0);
                if (m1) atomicOr(&smask[y - r0][1], m1);
            }
        }
    }
    __syncthreads();

    const float* att = (lid == 0) ? att0 : (lid == 1) ? att1
                     : (lid == 2) ? att2 : (lid == 3) ? att3 : att4;
    const float* attb = att + (size_t)b * npx;

    const float lo_c = 1e-7f;
    const float hi_c = (float)(1.0 - 1e-7);   // matches jnp.clip upper bound

    double acc = 0.0;
    // one float4 per iter (4 consecutive px: same row, same 64-bit mask word)
    for (int p0 = start + tid * 4; p0 < end; p0 += BLK * 4) {
        const float4 a = *reinterpret_cast<const float4*>(attb + p0);
        const int y  = p0 >> lw;
        const int x0 = p0 & (w - 1);
        const unsigned int bits =
            (unsigned int)(smask[y - r0][(x0 >> 6) & 1] >> (x0 & 63)) & 0xFu;
        const float v0 = fminf(fmaxf(a.x, lo_c), hi_c);
        const float v1 = fminf(fmaxf(a.y, lo_c), hi_c);
        const float v2 = fminf(fmaxf(a.z, lo_c), hi_c);
        const float v3 = fminf(fmaxf(a.w, lo_c), hi_c);
        acc += (bits & 1u) ? (double)(-logf(v0)) : (double)(-log1pf(-v0));
        acc += (bits & 2u) ? (double)(-logf(v1)) : (double)(-log1pf(-v1));
        acc += (bits & 4u) ? (double)(-logf(v2)) : (double)(-log1pf(-v2));
        acc += (bits & 8u) ? (double)(-logf(v3)) : (double)(-log1pf(-v3));
    }

    // ---- block reduction: wave butterfly + tiny LDS combine ----
    acc = wave_reduce(acc);
    if ((tid & 63) == 0) swave[tid >> 6] = acc;
    __syncthreads();
    if (tid == 0) {
        const double s = swave[0] + swave[1] + swave[2] + swave[3];
        const double wgt = s_hasvalid
            ? 1.0 / (5.0 * (double)B * (double)npx)
            : 0.0;
        __hip_atomic_store(&partial[bid], s * wgt,
                           __ATOMIC_RELEASE, __HIP_MEMORY_SCOPE_AGENT);
        const unsigned int old = __hip_atomic_fetch_add(
            counter, 1u, __ATOMIC_ACQ_REL, __HIP_MEMORY_SCOPE_AGENT);
        s_last = (old == (unsigned int)(nblk - 1)) ? 1 : 0;
    }
    __syncthreads();

    // ---- last finished block reduces all partials (fixed order: exact) ----
    if (s_last) {
        double v = 0.0;
        if (tid < nblk)
            v = __hip_atomic_load(&partial[tid],
                                  __ATOMIC_ACQUIRE, __HIP_MEMORY_SCOPE_AGENT);
        v = wave_reduce(v);
        if ((tid & 63) == 0) swave[tid >> 6] = v;
        __syncthreads();
        if (tid == 0)
            out[0] = (float)(swave[0] + swave[1] + swave[2] + swave[3]);
    }
}

extern "C" void kernel_launch(void* const* d_in, const int* in_sizes, int n_in,
                              void* d_out, int out_size, void* d_ws, size_t ws_size,
                              hipStream_t stream) {
    const float* att0  = (const float*)d_in[0];
    const float* att1  = (const float*)d_in[1];
    const float* att2  = (const float*)d_in[2];
    const float* att3  = (const float*)d_in[3];
    const float* att4  = (const float*)d_in[4];
    const float* bboxs = (const float*)d_in[5];
    const int*   Hp    = (const int*)d_in[6];
    const int*   Wp    = (const int*)d_in[7];
    float* out = (float*)d_out;

    const int B = in_sizes[5] / (NBOX * 5);   // 32
    const int nblk = B * 8;                   // 256 blocks

    double*       partial = (double*)d_ws;                       // nblk doubles
    unsigned int* counter = (unsigned int*)((char*)d_ws + 4096); // 1 uint

    hipMemsetAsync(counter, 0, sizeof(unsigned int), stream);
    level_loss_onekernel<<<nblk, BLK, 0, stream>>>(att0, att1, att2, att3, att4,
                                                   bboxs, Hp, Wp, partial, counter,
                                                   out, B, nblk);
}

// Round 7
// 77.655 us; speedup vs baseline: 1.6659x; 1.0623x over previous
//
#include <hip/hip_runtime.h>

#define NBOX 64
#define BLK  256

__device__ __forceinline__ unsigned long long range_mask(int x1, int x2, int base) {
    int lo = max(x1 - base, 0);
    int hi = min(x2 - base, 64);
    if (lo >= hi) return 0ull;
    unsigned long long m = (~0ull) >> (64 - (hi - lo));
    return m << lo;
}

__device__ __forceinline__ double wave_reduce(double v) {
    #pragma unroll
    for (int m = 1; m < 64; m <<= 1) v += __shfl_xor(v, m, 64);
    return v;
}

__global__ __launch_bounds__(BLK) void level_loss_partial(
    const float* __restrict__ att0, const float* __restrict__ att1,
    const float* __restrict__ att2, const float* __restrict__ att3,
    const float* __restrict__ att4,
    const float* __restrict__ bboxs,
    const int* __restrict__ Hp, const int* __restrict__ Wp,
    float* __restrict__ partial, int B)
{
    __shared__ unsigned long long smask[64][2];  // per-row x-coverage bitmask
    __shared__ int    s_hasvalid;
    __shared__ double swave[BLK / 64];

    const int tid  = threadIdx.x;
    const int bid  = blockIdx.x;
    const int b    = bid >> 3;          // 8 block-slots per batch
    const int slot = bid & 7;
    const int lid   = (slot < 4) ? 0 : (slot - 3);   // level id 0..4
    const int chunk = (slot < 4) ? slot : 0;
    const int lw  = 7 - lid;            // log2(width)
    const int w   = 1 << lw;
    const int npx = w << lw;
    const int start = chunk * 4096;
    const int end   = min(npx, start + 4096);
    const int r0    = start >> lw;              // first row of this chunk
    const int nrows = (end - start) >> lw;

    const float Hf = (float)(*Hp);
    const float Wf = (float)(*Wp);

    // ---- wave 0: zero masks, then rasterize boxes into row bitmasks ----
    if (tid < 64) {
        smask[tid][0] = 0ull;
        smask[tid][1] = 0ull;

        const float* bb = bboxs + ((size_t)b * NBOX + tid) * 5;
        const float x1 = bb[0], y1 = bb[1], x2 = bb[2], y2 = bb[3], lab = bb[4];
        const bool valid = (lab != -1.0f) && (x1 <= Wf) && (y1 <= Hf)
                        && (x2 <= Wf) && (y2 <= Hf);
        const float area = (x2 - x1) * (y2 - y1);
        const float base = (float)(32 << lid);
        const float min_a = base * base * 0.5f;                 // exact in f32
        const double bd   = (double)base * 1.58;
        const float max_a = (float)(bd * bd * 2.0);             // f64 -> f32, matches JAX promotion
        const bool lv = valid && (area >= min_a) && (area <= max_a);

        const unsigned long long mvalid = __ballot(valid);
        if (tid == 0) s_hasvalid = (mvalid != 0ull) ? 1 : 0;

        if (lv) {
            const float sx = (float)w / Wf;   // powers of two: exact
            const float sy = (float)w / Hf;
            const int ix1 = (int)fmaxf(floorf(x1 * sx), 0.0f);
            const int iy1 = (int)fmaxf(floorf(y1 * sy), 0.0f);
            const int ix2 = (int)fminf(ceilf(x2 * sx) + 1.0f, (float)w);
            const int iy2 = (int)fminf(ceilf(y2 * sy) + 1.0f, (float)w);
            const int ys = max(iy1, r0);
            const int ye = min(iy2, r0 + nrows);
            const unsigned long long m0 = range_mask(ix1, ix2, 0);
            const unsigned long long m1 = range_mask(ix1, ix2, 64);
            for (int y = ys; y < ye; ++y) {
                if (m0) atomicOr(&smask[y - r0][0], m0);
                if (m1) atomicOr(&smask[y - r0][1], m1);
            }
        }
    }
    __syncthreads();

    const float* att = (lid == 0) ? att0 : (lid == 1) ? att1
                     : (lid == 2) ? att2 : (lid == 3) ? att3 : att4;
    const float* attb = att + (size_t)b * npx;

    const float lo_c = 1e-7f;
    const float hi_c = (float)(1.0 - 1e-7);   // matches jnp.clip upper bound

    double acc = 0.0;
    // one float4 per iter (4 consecutive px: same row, same 64-bit mask word)
    for (int p0 = start + tid * 4; p0 < end; p0 += BLK * 4) {
        const float4 a = *reinterpret_cast<const float4*>(attb + p0);
        const int y  = p0 >> lw;
        const int x0 = p0 & (w - 1);
        const unsigned int bits =
            (unsigned int)(smask[y - r0][(x0 >> 6) & 1] >> (x0 & 63)) & 0xFu;
        const float v0 = fminf(fmaxf(a.x, lo_c), hi_c);
        const float v1 = fminf(fmaxf(a.y, lo_c), hi_c);
        const float v2 = fminf(fmaxf(a.z, lo_c), hi_c);
        const float v3 = fminf(fmaxf(a.w, lo_c), hi_c);
        acc += (bits & 1u) ? (double)(-logf(v0)) : (double)(-log1pf(-v0));
        acc += (bits & 2u) ? (double)(-logf(v1)) : (double)(-log1pf(-v1));
        acc += (bits & 4u) ? (double)(-logf(v2)) : (double)(-log1pf(-v2));
        acc += (bits & 8u) ? (double)(-logf(v3)) : (double)(-log1pf(-v3));
    }

    // ---- block reduction: wave butterfly + tiny LDS combine ----
    acc = wave_reduce(acc);
    if ((tid & 63) == 0) swave[tid >> 6] = acc;
    __syncthreads();
    if (tid == 0) {
        const double s = swave[0] + swave[1] + swave[2] + swave[3];
        const double wgt = s_hasvalid
            ? 1.0 / (5.0 * (double)B * (double)npx)
            : 0.0;
        partial[bid] = (float)(s * wgt);
    }
}

__global__ __launch_bounds__(64) void reduce_partials(
    const float* __restrict__ partial, int n, float* __restrict__ out)
{
    const int tid = threadIdx.x;
    double a = 0.0;
    for (int i = tid; i < n; i += 64) a += (double)partial[i];
    a = wave_reduce(a);
    if (tid == 0) out[0] = (float)a;
}

extern "C" void kernel_launch(void* const* d_in, const int* in_sizes, int n_in,
                              void* d_out, int out_size, void* d_ws, size_t ws_size,
                              hipStream_t stream) {
    const float* att0  = (const float*)d_in[0];
    const float* att1  = (const float*)d_in[1];
    const float* att2  = (const float*)d_in[2];
    const float* att3  = (const float*)d_in[3];
    const float* att4  = (const float*)d_in[4];
    const float* bboxs = (const float*)d_in[5];
    const int*   Hp    = (const int*)d_in[6];
    const int*   Wp    = (const int*)d_in[7];
    float* out = (float*)d_out;

    const int B = in_sizes[5] / (NBOX * 5);   // 32
    const int nblk = B * 8;                   // 256 blocks
    float* partial = (float*)d_ws;            // nblk floats

    level_loss_partial<<<nblk, BLK, 0, stream>>>(att0, att1, att2, att3, att4,
                                                 bboxs, Hp, Wp, partial, B);
    reduce_partials<<<1, 64, 0, stream>>>(partial, nblk, out);
}